// Round 4
// baseline (583.886 us; speedup 1.0000x reference)
//
#include <hip/hip_runtime.h>

// ---------------------------------------------------------------------------
// RGAT encoder: N=50000, E=800000, R=8, IN=H=128, B=10.
// R4: aggregate-then-transform. By linearity,
//   out[t] = sum_r ( sum_{e in rel r} a_e * x[src_e] ) @ W_r
// so the 102 MB xW intermediate disappears. Per layer ONE fused kernel:
//   per target: exact softmax (m, den) -> normalized gather of x rows (LLC-hot,
//   12.8 MB) into per-(t, r) register accumulators -> g tile in LDS ->
//   MFMA g[32x1024] @ WTcat[1024x128] -> relu(+bias).
// Layer-1 epilogue: store h1 + compute layer-2 score table (MFMA vs wqk2).
// Layer-2 epilogue: fuse final linear (A = Wl rows) -> f32 out. CSR built once.
// ---------------------------------------------------------------------------

typedef unsigned int uint;
typedef unsigned short ushort_t;

using bf16x8 = __attribute__((ext_vector_type(8))) __bf16;
using f32x4  = __attribute__((ext_vector_type(4))) float;

__device__ __forceinline__ ushort_t fToBf(float f) {
  uint u = __float_as_uint(f);
  u += 0x7FFFu + ((u >> 16) & 1);   // round-to-nearest-even
  return (ushort_t)(u >> 16);
}
__device__ __forceinline__ float bfToF(ushort_t h) {
  return __uint_as_float(((uint)h) << 16);
}

// ------------------------------- CSR build ---------------------------------

__global__ void k_count(const int* __restrict__ tgt, int* __restrict__ deg, int E) {
  int e = blockIdx.x * 256 + threadIdx.x;
  if (e < E) atomicAdd(&deg[tgt[e]], 1);
}

__global__ void k_scanA(const int* __restrict__ deg, int* __restrict__ incl,
                        int* __restrict__ bsum, int n) {
  __shared__ int s[256];
  int tid = threadIdx.x;
  int i = blockIdx.x * 256 + tid;
  int v = (i < n) ? deg[i] : 0;
  s[tid] = v;
  __syncthreads();
  for (int off = 1; off < 256; off <<= 1) {
    int t = (tid >= off) ? s[tid - off] : 0;
    __syncthreads();
    s[tid] += t;
    __syncthreads();
  }
  if (i < n) incl[i] = s[tid];
  if (tid == 255) bsum[blockIdx.x] = s[255];
}

__global__ void k_scanB(int* __restrict__ bsum, int nb) {
  __shared__ int s[256];
  int tid = threadIdx.x;
  int v = (tid < nb) ? bsum[tid] : 0;
  s[tid] = v;
  __syncthreads();
  for (int off = 1; off < 256; off <<= 1) {
    int t = (tid >= off) ? s[tid - off] : 0;
    __syncthreads();
    s[tid] += t;
    __syncthreads();
  }
  if (tid < nb) bsum[tid] = s[tid] - v;   // exclusive
}

__global__ void k_scanC(const int* __restrict__ deg, const int* __restrict__ incl,
                        const int* __restrict__ bsum, int* __restrict__ rowptr,
                        int n, int E) {
  int i = blockIdx.x * 256 + threadIdx.x;
  if (i < n) {
    rowptr[i] = bsum[blockIdx.x] + incl[i] - deg[i];
    if (i == n - 1) rowptr[n] = E;
  }
}

__global__ void k_scatter(const int* __restrict__ src, const int* __restrict__ tgt,
                          const int* __restrict__ et, const int* __restrict__ rowptr,
                          int* __restrict__ cursor, int* __restrict__ sorted, int E) {
  int e = blockIdx.x * 256 + threadIdx.x;
  if (e >= E) return;
  int t = tgt[e];
  int pos = atomicAdd(&cursor[t], 1);
  sorted[rowptr[t] + pos] = src[e] | (et[e] << 16);   // src < 65536, rel < 8
}

// ------------------------------ conversions --------------------------------

__global__ void k_cvt(const float* __restrict__ in, ushort_t* __restrict__ out, int n4) {
  int i = blockIdx.x * 256 + threadIdx.x;
  if (i >= n4) return;
  float4 v = ((const float4*)in)[i];
  ushort4 o;
  o.x = fToBf(v.x); o.y = fToBf(v.y); o.z = fToBf(v.z); o.w = fToBf(v.w);
  ((ushort4*)out)[i] = o;
}

// WTcat[layer][n][r*128+k] = W_layer[r][k][n]  (bf16) — A-operand rows for
// the fused GEMM (m = out-channel n, k-dim = r*128+k over 1024).
__global__ void k_wT(const float* __restrict__ W1, const float* __restrict__ W2,
                     ushort_t* __restrict__ WT) {
  int b = blockIdx.x;                 // layer*1024 + n*8 + r
  int layer = b >> 10;
  int n = (b >> 3) & 127, r = b & 7;
  const float* W = layer ? W2 : W1;
  int k = threadIdx.x;                // 128
  WT[(size_t)(layer * 128 + n) * 1024 + r * 128 + k] =
      fToBf(W[((size_t)r * 128 + k) * 128 + n]);
}

// wqk[layer][16][128] bf16: rows 0..7 = Wq[r] = W_r @ q, rows 8..15 = Wk[r].
__global__ void k_wqwk(const float* __restrict__ W1, const float* __restrict__ q1,
                       const float* __restrict__ k1, const float* __restrict__ W2,
                       const float* __restrict__ q2, const float* __restrict__ k2,
                       ushort_t* __restrict__ wqk) {
  int g = blockIdx.x * 256 + threadIdx.x;   // 0..4095
  if (g >= 4096) return;
  int layer = g >> 11;
  int which = (g >> 10) & 1;
  int idx = g & 1023;                        // r*128 + kin
  const float* w = (layer ? W2 : W1) + (size_t)idx * 128;
  const float* v = layer ? (which ? k2 : q2) : (which ? k1 : q1);
  float s = 0.f;
  #pragma unroll 8
  for (int h = 0; h < 128; h++) s += w[h] * v[h];
  int r = idx >> 7, kin = idx & 127;
  wqk[(size_t)layer * 2048 + ((which << 3) + r) * 128 + kin] = fToBf(s);
}

// ------------------------- layer-1 score table -----------------------------
// stbl[node][0..7] = x.Wq[r], [8..15] = x.Wk[r]. A = wqk rows, B = x rows.

__global__ __launch_bounds__(256) void
k_stbl(const ushort_t* __restrict__ xb, const ushort_t* __restrict__ wqk,
       float* __restrict__ stbl, int M) {
  int tid = threadIdx.x, wv = tid >> 6, lane = tid & 63;
  int l15 = lane & 15, quad = lane >> 4;
  int node0 = blockIdx.x * 128 + wv * 32;
  bf16x8 aq[4];
  #pragma unroll
  for (int kb = 0; kb < 4; kb++)
    aq[kb] = *(const bf16x8*)(wqk + (size_t)l15 * 128 + kb * 32 + quad * 8);
  #pragma unroll
  for (int nt = 0; nt < 2; nt++) {
    int node = node0 + nt * 16 + l15;
    int nc = node < M ? node : M - 1;
    f32x4 a = {};
    #pragma unroll
    for (int kb = 0; kb < 4; kb++) {
      bf16x8 bf = *(const bf16x8*)(xb + (size_t)nc * 128 + kb * 32 + quad * 8);
      a = __builtin_amdgcn_mfma_f32_16x16x32_bf16(aq[kb], bf, a, 0, 0, 0);
    }
    if (node < M) {
      #pragma unroll
      for (int reg = 0; reg < 4; reg++)
        stbl[(size_t)node * 16 + quad * 4 + reg] = a[reg];
    }
  }
}

// --------------------------- fused RGAT layer ------------------------------
// Block = 256 thr (4 waves) = 32 targets; wave handles 8 targets sequentially.
// EPI 1: store h (bf16) + next-layer score table.  EPI 2: fuse final linear.

#define ACCR(R_, W_, V_) {                                           \
  float lo_ = bfToF((ushort_t)((V_) & 0xFFFF));                      \
  float hi_ = bfToF((ushort_t)((V_) >> 16));                         \
  switch (R_) {                                                      \
    case 0: acc[0]  += (W_) * lo_; acc[1]  += (W_) * hi_; break;     \
    case 1: acc[2]  += (W_) * lo_; acc[3]  += (W_) * hi_; break;     \
    case 2: acc[4]  += (W_) * lo_; acc[5]  += (W_) * hi_; break;     \
    case 3: acc[6]  += (W_) * lo_; acc[7]  += (W_) * hi_; break;     \
    case 4: acc[8]  += (W_) * lo_; acc[9]  += (W_) * hi_; break;     \
    case 5: acc[10] += (W_) * lo_; acc[11] += (W_) * hi_; break;     \
    case 6: acc[12] += (W_) * lo_; acc[13] += (W_) * hi_; break;     \
    default: acc[14] += (W_) * lo_; acc[15] += (W_) * hi_; break; } }

template <int EPI>
__global__ __launch_bounds__(256, 2) void
k_fused(const ushort_t* __restrict__ feat,    // [N][128] bf16 (xbf or h1)
        const float* __restrict__ stbl_in,    // [N][16]
        const int* __restrict__ rowptr, const int* __restrict__ sorted,
        const ushort_t* __restrict__ WTcat,   // [128][1024] bf16 (this layer)
        const float* __restrict__ bias,       // [128] conv bias
        const ushort_t* __restrict__ wqk2,    // EPI1: [16][128]
        float* __restrict__ stbl_out,         // EPI1
        ushort_t* __restrict__ h_out,         // EPI1
        const ushort_t* __restrict__ wlbf,    // EPI2: [128][128]
        const float* __restrict__ bl,         // EPI2
        float* __restrict__ out,              // EPI2
        int n) {
  __shared__ __align__(16) ushort_t g[32 * 1032];   // g[t][r*128+k], pad 8
  __shared__ __align__(16) ushort_t ht[32 * 136];   // h tile [t][ch], pad 8
  int tid = threadIdx.x, wv = tid >> 6, lane = tid & 63;
  int l15 = lane & 15, quad = lane >> 4;
  int t0 = blockIdx.x * 32;

  // ---------------- gather phase: 8 targets per wave ----------------
  for (int ti = 0; ti < 8; ti++) {
    int tt = wv * 8 + ti;
    int t = t0 + tt;
    float acc[16];
    #pragma unroll
    for (int i = 0; i < 16; i++) acc[i] = 0.f;
    if (t < n) {
      int e0 = rowptr[t], e1 = rowptr[t + 1];
      // pass 1: exact per-target max + denominator (online across chunks)
      float m = -INFINITY, den = 0.f;
      for (int base = e0; base < e1; base += 64) {
        int cnt = min(64, e1 - base);
        float alpha = -INFINITY;
        if (lane < cnt) {
          int pk = sorted[base + lane];
          int s = pk & 0xFFFF, r = pk >> 16;
          float a = stbl_in[(size_t)t * 16 + r] + stbl_in[(size_t)s * 16 + 8 + r];
          alpha = (a >= 0.f) ? a : 0.2f * a;   // leaky_relu 0.2
        }
        float cm = alpha;
        #pragma unroll
        for (int off = 32; off; off >>= 1) cm = fmaxf(cm, __shfl_xor(cm, off, 64));
        float nm = fmaxf(m, cm);
        den *= __expf(m - nm);
        float ws = (lane < cnt) ? __expf(alpha - nm) : 0.f;
        #pragma unroll
        for (int off = 32; off; off >>= 1) ws += __shfl_xor(ws, off, 64);
        den += ws;
        m = nm;
      }
      float invden = (den > 0.f) ? 1.f / (den + 1e-16f) : 0.f;
      // pass 2: normalized weights, gather x rows (lane = channel pair)
      for (int base = e0; base < e1; base += 64) {
        int cnt = min(64, e1 - base);
        float w = 0.f;
        int pk = 0;
        if (lane < cnt) {
          pk = sorted[base + lane];
          int s = pk & 0xFFFF, r = pk >> 16;
          float a = stbl_in[(size_t)t * 16 + r] + stbl_in[(size_t)s * 16 + 8 + r];
          a = (a >= 0.f) ? a : 0.2f * a;
          w = __expf(a - m) * invden;
        }
        uint wu = __float_as_uint(w);
        int j = 0;
        for (; j + 3 < cnt; j += 4) {      // 4 loads in flight
          int p0 = __builtin_amdgcn_readlane(pk, j);
          int p1 = __builtin_amdgcn_readlane(pk, j + 1);
          int p2 = __builtin_amdgcn_readlane(pk, j + 2);
          int p3 = __builtin_amdgcn_readlane(pk, j + 3);
          float w0 = __uint_as_float(__builtin_amdgcn_readlane(wu, j));
          float w1 = __uint_as_float(__builtin_amdgcn_readlane(wu, j + 1));
          float w2 = __uint_as_float(__builtin_amdgcn_readlane(wu, j + 2));
          float w3 = __uint_as_float(__builtin_amdgcn_readlane(wu, j + 3));
          uint v0 = *(const uint*)(feat + (size_t)(p0 & 0xFFFF) * 128 + (lane << 1));
          uint v1 = *(const uint*)(feat + (size_t)(p1 & 0xFFFF) * 128 + (lane << 1));
          uint v2 = *(const uint*)(feat + (size_t)(p2 & 0xFFFF) * 128 + (lane << 1));
          uint v3 = *(const uint*)(feat + (size_t)(p3 & 0xFFFF) * 128 + (lane << 1));
          ACCR(p0 >> 16, w0, v0);
          ACCR(p1 >> 16, w1, v1);
          ACCR(p2 >> 16, w2, v2);
          ACCR(p3 >> 16, w3, v3);
        }
        for (; j < cnt; j++) {
          int p0 = __builtin_amdgcn_readlane(pk, j);
          float w0 = __uint_as_float(__builtin_amdgcn_readlane(wu, j));
          uint v0 = *(const uint*)(feat + (size_t)(p0 & 0xFFFF) * 128 + (lane << 1));
          ACCR(p0 >> 16, w0, v0);
        }
      }
    }
    // dump g rows (all 8 relations written -> no LDS zeroing needed)
    #pragma unroll
    for (int r = 0; r < 8; r++) {
      uint p = (uint)fToBf(acc[2 * r]) | ((uint)fToBf(acc[2 * r + 1]) << 16);
      *(uint*)(g + (size_t)tt * 1032 + r * 128 + (lane << 1)) = p;
    }
  }
  __syncthreads();

  // ---------------- transform: out_ch = WTcat[128x1024] . g[t][1024] -------
  // wave wv owns m-tiles {2wv, 2wv+1}; n-tiles (targets) {0,1}.
  f32x4 ac[2][2] = {};
  for (int kk = 0; kk < 32; kk++) {
    bf16x8 b0 = *(const bf16x8*)(g + (size_t)l15 * 1032 + kk * 32 + quad * 8);
    bf16x8 b1 = *(const bf16x8*)(g + (size_t)(16 + l15) * 1032 + kk * 32 + quad * 8);
    #pragma unroll
    for (int mi = 0; mi < 2; mi++) {
      bf16x8 af = *(const bf16x8*)(WTcat + (size_t)((wv * 2 + mi) * 16 + l15) * 1024 + kk * 32 + quad * 8);
      ac[mi][0] = __builtin_amdgcn_mfma_f32_16x16x32_bf16(af, b0, ac[mi][0], 0, 0, 0);
      ac[mi][1] = __builtin_amdgcn_mfma_f32_16x16x32_bf16(af, b1, ac[mi][1], 0, 0, 0);
    }
  }
  // relu(v + bias) -> bf16 -> ht[t][ch]  (D: row=ch, col=target)
  #pragma unroll
  for (int mi = 0; mi < 2; mi++) {
    int ch0 = (wv * 2 + mi) * 16 + quad * 4;
    #pragma unroll
    for (int ni = 0; ni < 2; ni++) {
      uint2 p;
      float a0 = fmaxf(ac[mi][ni][0] + bias[ch0], 0.f);
      float a1 = fmaxf(ac[mi][ni][1] + bias[ch0 + 1], 0.f);
      float a2 = fmaxf(ac[mi][ni][2] + bias[ch0 + 2], 0.f);
      float a3 = fmaxf(ac[mi][ni][3] + bias[ch0 + 3], 0.f);
      p.x = (uint)fToBf(a0) | ((uint)fToBf(a1) << 16);
      p.y = (uint)fToBf(a2) | ((uint)fToBf(a3) << 16);
      *(uint2*)(ht + (size_t)(ni * 16 + l15) * 136 + ch0) = p;
    }
  }
  __syncthreads();

  if constexpr (EPI == 1) {
    // store h (coalesced) + next-layer score table (MFMA vs wqk2)
    for (int c = tid; c < 512; c += 256) {
      int row = c >> 4, off = (c & 15) * 8;
      int t = t0 + row;
      if (t < n)
        *(int4*)(h_out + (size_t)t * 128 + off) = *(const int4*)(ht + (size_t)row * 136 + off);
    }
    bf16x8 aq[4];
    #pragma unroll
    for (int kb = 0; kb < 4; kb++)
      aq[kb] = *(const bf16x8*)(wqk2 + (size_t)l15 * 128 + kb * 32 + quad * 8);
    #pragma unroll
    for (int ni = 0; ni < 2; ni++) {
      f32x4 a = {};
      #pragma unroll
      for (int kb = 0; kb < 4; kb++) {
        bf16x8 bf = *(const bf16x8*)(ht + (size_t)(ni * 16 + l15) * 136 + kb * 32 + quad * 8);
        a = __builtin_amdgcn_mfma_f32_16x16x32_bf16(aq[kb], bf, a, 0, 0, 0);
      }
      int t = t0 + ni * 16 + l15;
      if (t < n) {
        #pragma unroll
        for (int reg = 0; reg < 4; reg++)
          stbl_out[(size_t)t * 16 + quad * 4 + reg] = a[reg];
      }
    }
  } else {
    // fused final linear: out = ht @ Wl^T + bl (f32). A = Wl rows, B = ht rows.
    float* ft = (float*)g;    // g dead after main MFMA (post-barrier)
    f32x4 a2[2][2] = {};
    #pragma unroll
    for (int kb = 0; kb < 4; kb++) {
      bf16x8 b0 = *(const bf16x8*)(ht + (size_t)l15 * 136 + kb * 32 + quad * 8);
      bf16x8 b1 = *(const bf16x8*)(ht + (size_t)(16 + l15) * 136 + kb * 32 + quad * 8);
      #pragma unroll
      for (int mi = 0; mi < 2; mi++) {
        bf16x8 af = *(const bf16x8*)(wlbf + (size_t)((wv * 2 + mi) * 16 + l15) * 128 + kb * 32 + quad * 8);
        a2[mi][0] = __builtin_amdgcn_mfma_f32_16x16x32_bf16(af, b0, a2[mi][0], 0, 0, 0);
        a2[mi][1] = __builtin_amdgcn_mfma_f32_16x16x32_bf16(af, b1, a2[mi][1], 0, 0, 0);
      }
    }
    #pragma unroll
    for (int mi = 0; mi < 2; mi++) {
      int ch0 = (wv * 2 + mi) * 16 + quad * 4;
      #pragma unroll
      for (int ni = 0; ni < 2; ni++) {
        float4 v;
        v.x = a2[mi][ni][0] + bl[ch0];
        v.y = a2[mi][ni][1] + bl[ch0 + 1];
        v.z = a2[mi][ni][2] + bl[ch0 + 2];
        v.w = a2[mi][ni][3] + bl[ch0 + 3];
        *(float4*)(ft + (size_t)(ni * 16 + l15) * 132 + ch0) = v;
      }
    }
    __syncthreads();
    for (int c = tid; c < 1024; c += 256) {
      int row = c >> 5, off = (c & 31) * 4;
      int t = t0 + row;
      if (t < n)
        *(float4*)(out + (size_t)t * 128 + off) = *(const float4*)(ft + (size_t)row * 132 + off);
    }
  }
}

// ------------------------------- launcher ----------------------------------

extern "C" void kernel_launch(void* const* d_in, const int* in_sizes, int n_in,
                              void* d_out, int out_size, void* d_ws, size_t ws_size,
                              hipStream_t stream) {
  const float* x   = (const float*)d_in[0];
  const int* ei    = (const int*)d_in[1];
  const int* etype = (const int*)d_in[2];
  const float* W1  = (const float*)d_in[4];
  const float* q1  = (const float*)d_in[5];
  const float* k1  = (const float*)d_in[6];
  const float* b1  = (const float*)d_in[7];
  const float* W2  = (const float*)d_in[8];
  const float* q2  = (const float*)d_in[9];
  const float* k2  = (const float*)d_in[10];
  const float* b2  = (const float*)d_in[11];
  const float* Wl  = (const float*)d_in[12];
  const float* bl  = (const float*)d_in[13];
  float* out       = (float*)d_out;

  const int N = in_sizes[0] / 128;   // 50000
  const int E = in_sizes[2];         // 800000

  char* ws = (char*)d_ws;
  size_t off = 0;
  auto alloc = [&](size_t bytes) {
    size_t o = off;
    off = (off + bytes + 255) & ~(size_t)255;
    return o;
  };

  ushort_t* xbf   = (ushort_t*)(ws + alloc((size_t)N * 128 * 2));
  ushort_t* h1    = (ushort_t*)(ws + alloc((size_t)N * 128 * 2));
  ushort_t* WTcat = (ushort_t*)(ws + alloc((size_t)2 * 128 * 1024 * 2));
  ushort_t* wlbf  = (ushort_t*)(ws + alloc(128 * 128 * 2));
  ushort_t* wqk   = (ushort_t*)(ws + alloc(2 * 16 * 128 * 2));
  float* stblA    = (float*)(ws + alloc((size_t)N * 16 * 4));
  float* stblB    = (float*)(ws + alloc((size_t)N * 16 * 4));
  int* deg        = (int*)(ws + alloc((size_t)N * 4));
  int* cursor     = (int*)(ws + alloc((size_t)N * 4));
  int* incl       = (int*)(ws + alloc((size_t)N * 4));
  int* rowptr     = (int*)(ws + alloc((size_t)(N + 1) * 4));
  int* bsum       = (int*)(ws + alloc(256 * 4));
  int* sorted     = (int*)(ws + alloc((size_t)E * 4));
  (void)ws_size; (void)n_in; (void)out_size;

  const int* srcp = ei;
  const int* tgtp = ei + E;

  int gE = (E + 255) / 256;
  int gN = (N + 255) / 256;
  int gS = (N + 127) / 128;     // k_stbl
  int gF = (N + 31) / 32;       // k_fused: 1563 blocks

  // CSR build (once; same graph both layers)
  hipMemsetAsync(deg, 0, (size_t)N * 4, stream);
  hipMemsetAsync(cursor, 0, (size_t)N * 4, stream);
  k_count<<<gE, 256, 0, stream>>>(tgtp, deg, E);
  k_scanA<<<gN, 256, 0, stream>>>(deg, incl, bsum, N);
  k_scanB<<<1, 256, 0, stream>>>(bsum, gN);
  k_scanC<<<gN, 256, 0, stream>>>(deg, incl, bsum, rowptr, N, E);
  k_scatter<<<gE, 256, 0, stream>>>(srcp, tgtp, etype, rowptr, cursor, sorted, E);

  // conversions + weight prep
  k_cvt<<<(N * 128 / 4 + 255) / 256, 256, 0, stream>>>(x, xbf, N * 128 / 4);
  k_cvt<<<(128 * 128 / 4 + 255) / 256, 256, 0, stream>>>(Wl, wlbf, 128 * 128 / 4);
  k_wT<<<2048, 128, 0, stream>>>(W1, W2, WTcat);
  k_wqwk<<<16, 256, 0, stream>>>(W1, q1, k1, W2, q2, k2, wqk);

  // layer-1 score table
  k_stbl<<<gS, 256, 0, stream>>>(xbf, wqk, stblA, N);

  // layer 1 (writes h1 + stblB)
  k_fused<1><<<gF, 256, 0, stream>>>(xbf, stblA, rowptr, sorted, WTcat, b1,
                                     wqk + 2048, stblB, h1,
                                     nullptr, nullptr, nullptr, N);
  // layer 2 + fused final linear (writes f32 out)
  k_fused<2><<<gF, 256, 0, stream>>>(h1, stblB, rowptr, sorted,
                                     WTcat + (size_t)128 * 1024, b2,
                                     nullptr, nullptr, nullptr,
                                     wlbf, bl, out, N);
}

// Round 5
// 486.042 us; speedup vs baseline: 1.2013x; 1.2013x over previous
//
#include <hip/hip_runtime.h>

// ---------------------------------------------------------------------------
// RGAT encoder: N=50000, E=800000, R=8, IN=H=128, B=10.
// R5: aggregate-then-transform, restructured for TLP:
//   k_weights: per-target softmax -> normalized edge weights, + counting sort
//              of each target's edges by relation (kills the gather switch).
//   k_layer  : 1024-thr blocks (16 waves, 32 targets, 32 waves/CU):
//              gather x rows (r-sorted, flush-on-r-change, 2-reg acc) into
//              LDS g[32][1024] -> MFMA g @ WTcat -> relu+bias -> ht.
//              EPI1: store h + next-layer score table. EPI2: fused final linear.
// No 100 MB intermediate; x re-reads are L2/LLC-hot. CSR built once.
// ---------------------------------------------------------------------------

typedef unsigned int uint;
typedef unsigned short ushort_t;

using bf16x8 = __attribute__((ext_vector_type(8))) __bf16;
using f32x4  = __attribute__((ext_vector_type(4))) float;

__device__ __forceinline__ ushort_t fToBf(float f) {
  uint u = __float_as_uint(f);
  u += 0x7FFFu + ((u >> 16) & 1);   // round-to-nearest-even
  return (ushort_t)(u >> 16);
}
__device__ __forceinline__ float bfToF(ushort_t h) {
  return __uint_as_float(((uint)h) << 16);
}

// ------------------------------- CSR build ---------------------------------

__global__ void k_count(const int* __restrict__ tgt, int* __restrict__ deg, int E) {
  int e = blockIdx.x * 256 + threadIdx.x;
  if (e < E) atomicAdd(&deg[tgt[e]], 1);
}

__global__ void k_scanA(const int* __restrict__ deg, int* __restrict__ incl,
                        int* __restrict__ bsum, int n) {
  __shared__ int s[256];
  int tid = threadIdx.x;
  int i = blockIdx.x * 256 + tid;
  int v = (i < n) ? deg[i] : 0;
  s[tid] = v;
  __syncthreads();
  for (int off = 1; off < 256; off <<= 1) {
    int t = (tid >= off) ? s[tid - off] : 0;
    __syncthreads();
    s[tid] += t;
    __syncthreads();
  }
  if (i < n) incl[i] = s[tid];
  if (tid == 255) bsum[blockIdx.x] = s[255];
}

__global__ void k_scanB(int* __restrict__ bsum, int nb) {
  __shared__ int s[256];
  int tid = threadIdx.x;
  int v = (tid < nb) ? bsum[tid] : 0;
  s[tid] = v;
  __syncthreads();
  for (int off = 1; off < 256; off <<= 1) {
    int t = (tid >= off) ? s[tid - off] : 0;
    __syncthreads();
    s[tid] += t;
    __syncthreads();
  }
  if (tid < nb) bsum[tid] = s[tid] - v;   // exclusive
}

__global__ void k_scanC(const int* __restrict__ deg, const int* __restrict__ incl,
                        const int* __restrict__ bsum, int* __restrict__ rowptr,
                        int n, int E) {
  int i = blockIdx.x * 256 + threadIdx.x;
  if (i < n) {
    rowptr[i] = bsum[blockIdx.x] + incl[i] - deg[i];
    if (i == n - 1) rowptr[n] = E;
  }
}

__global__ void k_scatter(const int* __restrict__ src, const int* __restrict__ tgt,
                          const int* __restrict__ et, const int* __restrict__ rowptr,
                          int* __restrict__ cursor, int* __restrict__ sorted, int E) {
  int e = blockIdx.x * 256 + threadIdx.x;
  if (e >= E) return;
  int t = tgt[e];
  int pos = atomicAdd(&cursor[t], 1);
  sorted[rowptr[t] + pos] = src[e] | (et[e] << 16);   // src < 65536, rel < 8
}

// ------------------------------ conversions --------------------------------

__global__ void k_cvt(const float* __restrict__ in, ushort_t* __restrict__ out, int n4) {
  int i = blockIdx.x * 256 + threadIdx.x;
  if (i >= n4) return;
  float4 v = ((const float4*)in)[i];
  ushort4 o;
  o.x = fToBf(v.x); o.y = fToBf(v.y); o.z = fToBf(v.z); o.w = fToBf(v.w);
  ((ushort4*)out)[i] = o;
}

// WTcat[layer][n][r*128+k] = W_layer[r][k][n] (bf16) — A-operand rows.
__global__ void k_wT(const float* __restrict__ W1, const float* __restrict__ W2,
                     ushort_t* __restrict__ WT) {
  int b = blockIdx.x;                 // layer*1024 + n*8 + r
  int layer = b >> 10;
  int n = (b >> 3) & 127, r = b & 7;
  const float* W = layer ? W2 : W1;
  int k = threadIdx.x;                // 128
  WT[(size_t)(layer * 128 + n) * 1024 + r * 128 + k] =
      fToBf(W[((size_t)r * 128 + k) * 128 + n]);
}

// wqk[layer][16][128] bf16: rows 0..7 = Wq[r] = W_r @ q, rows 8..15 = Wk[r].
__global__ void k_wqwk(const float* __restrict__ W1, const float* __restrict__ q1,
                       const float* __restrict__ k1, const float* __restrict__ W2,
                       const float* __restrict__ q2, const float* __restrict__ k2,
                       ushort_t* __restrict__ wqk) {
  int g = blockIdx.x * 256 + threadIdx.x;   // 0..4095
  if (g >= 4096) return;
  int layer = g >> 11;
  int which = (g >> 10) & 1;
  int idx = g & 1023;                        // r*128 + kin
  const float* w = (layer ? W2 : W1) + (size_t)idx * 128;
  const float* v = layer ? (which ? k2 : q2) : (which ? k1 : q1);
  float s = 0.f;
  #pragma unroll 8
  for (int h = 0; h < 128; h++) s += w[h] * v[h];
  int r = idx >> 7, kin = idx & 127;
  wqk[(size_t)layer * 2048 + ((which << 3) + r) * 128 + kin] = fToBf(s);
}

// ------------------------- layer-1 score table -----------------------------

__global__ __launch_bounds__(256) void
k_stbl(const ushort_t* __restrict__ xb, const ushort_t* __restrict__ wqk,
       float* __restrict__ stbl, int M) {
  int tid = threadIdx.x, wv = tid >> 6, lane = tid & 63;
  int l15 = lane & 15, quad = lane >> 4;
  int node0 = blockIdx.x * 128 + wv * 32;
  bf16x8 aq[4];
  #pragma unroll
  for (int kb = 0; kb < 4; kb++)
    aq[kb] = *(const bf16x8*)(wqk + (size_t)l15 * 128 + kb * 32 + quad * 8);
  #pragma unroll
  for (int nt = 0; nt < 2; nt++) {
    int node = node0 + nt * 16 + l15;
    int nc = node < M ? node : M - 1;
    f32x4 a = {};
    #pragma unroll
    for (int kb = 0; kb < 4; kb++) {
      bf16x8 bf = *(const bf16x8*)(xb + (size_t)nc * 128 + kb * 32 + quad * 8);
      a = __builtin_amdgcn_mfma_f32_16x16x32_bf16(aq[kb], bf, a, 0, 0, 0);
    }
    if (node < M) {
      #pragma unroll
      for (int reg = 0; reg < 4; reg++)
        stbl[(size_t)node * 16 + quad * 4 + reg] = a[reg];
    }
  }
}

// ------------------------- edge weights + r-sort ---------------------------
// One wave/target: exact softmax -> normalized w per edge; counting sort by
// relation within each 64-edge chunk (stable by lane) -> sorted2/wts.

__global__ __launch_bounds__(256) void
k_weights(const float* __restrict__ stbl, const int* __restrict__ rowptr,
          const int* __restrict__ sorted, int* __restrict__ sorted2,
          float* __restrict__ wts, int n) {
  int wv = threadIdx.x >> 6, lane = threadIdx.x & 63;
  int t = blockIdx.x * 4 + wv;
  if (t >= n) return;
  int e0 = rowptr[t], e1 = rowptr[t + 1];
  if (e0 >= e1) return;

  float m = -INFINITY, den = 0.f;
  for (int base = e0; base < e1; base += 64) {
    int cnt = min(64, e1 - base);
    float alpha = -INFINITY;
    if (lane < cnt) {
      int pk = sorted[base + lane];
      int s = pk & 0xFFFF, r = pk >> 16;
      float a = stbl[(size_t)t * 16 + r] + stbl[(size_t)s * 16 + 8 + r];
      alpha = (a >= 0.f) ? a : 0.2f * a;   // leaky_relu 0.2
    }
    float cm = alpha;
    #pragma unroll
    for (int off = 32; off; off >>= 1) cm = fmaxf(cm, __shfl_xor(cm, off, 64));
    float nm = fmaxf(m, cm);
    den *= __expf(m - nm);
    float ws_ = (lane < cnt) ? __expf(alpha - nm) : 0.f;
    #pragma unroll
    for (int off = 32; off; off >>= 1) ws_ += __shfl_xor(ws_, off, 64);
    den += ws_;
    m = nm;
  }
  float invden = 1.f / (den + 1e-16f);

  for (int base = e0; base < e1; base += 64) {
    int cnt = min(64, e1 - base);
    int pk = 0, r = 8;                 // r=8 sentinel: never matches a bucket
    float w = 0.f;
    if (lane < cnt) {
      pk = sorted[base + lane];
      int s = pk & 0xFFFF; r = pk >> 16;
      float a = stbl[(size_t)t * 16 + r] + stbl[(size_t)s * 16 + 8 + r];
      a = (a >= 0.f) ? a : 0.2f * a;
      w = __expf(a - m) * invden;
    }
    unsigned long long below = (1ull << lane) - 1ull;
    int total = 0, rank = 0;
    #pragma unroll
    for (int c = 0; c < 8; c++) {
      unsigned long long mb = __ballot(r == c);
      if (r == c) rank = total + __popcll(mb & below);
      total += __popcll(mb);
    }
    if (lane < cnt) {
      sorted2[base + rank] = pk;
      wts[base + rank] = w;
    }
  }
}

// ----------------------------- fused layer ---------------------------------
// 1024 thr = 16 waves = 32 targets (2/wave). Gather: all 64 lanes cover the
// 128 channels (2 ch/lane); edges r-sorted -> flush 2-reg acc on r change.
// Transform: waves 0-7, m-tile = wv, both n-tiles. EPI as R4.

template <int EPI>
__global__ __launch_bounds__(1024, 8) void
k_layer(const ushort_t* __restrict__ feat,    // [N][128] bf16
        const int* __restrict__ rowptr, const int* __restrict__ sorted2,
        const float* __restrict__ wts,
        const ushort_t* __restrict__ WTcat,   // [128][1024] this layer
        const float* __restrict__ bias,
        const ushort_t* __restrict__ wqk2, float* __restrict__ stbl_out,
        ushort_t* __restrict__ h_out,         // EPI1
        const ushort_t* __restrict__ wlbf, const float* __restrict__ bl,
        float* __restrict__ out,              // EPI2
        int n) {
  __shared__ __align__(16) ushort_t gs[32 * 1032];
  __shared__ __align__(16) ushort_t ht[32 * 136];
  int tid = threadIdx.x, wv = tid >> 6, lane = tid & 63;
  int l15 = lane & 15, quad = lane >> 4;
  int t0 = blockIdx.x * 32;
  int col = lane << 1;                 // channel pair (x2 ushort)

  // ---------------- gather: 2 targets per wave ----------------
  for (int sub = 0; sub < 2; sub++) {
    int tt = wv * 2 + sub;
    int t = t0 + tt;
    ushort_t* grow = gs + (size_t)tt * 1032;
    uint wmask = 0;
    if (t < n) {
      int e0 = rowptr[t], e1 = rowptr[t + 1];
      float a0 = 0.f, a1 = 0.f;
      int rcur = -1;
      for (int base = e0; base < e1; base += 64) {
        int cnt = min(64, e1 - base);
        int pk = 0; uint wu = 0;
        if (lane < cnt) {
          pk = sorted2[base + lane];
          wu = __float_as_uint(wts[base + lane]);
        }
        int pkj = __builtin_amdgcn_readlane(pk, 0);
        uint v = *(const uint*)(feat + (size_t)(pkj & 0xFFFF) * 128 + col);
        for (int j = 0; j < cnt; j++) {
          int jn = (j + 1 < cnt) ? j + 1 : j;
          int pkn = __builtin_amdgcn_readlane(pk, jn);
          uint vn = *(const uint*)(feat + (size_t)(pkn & 0xFFFF) * 128 + col);
          float wj = __uint_as_float(__builtin_amdgcn_readlane(wu, j));
          int rj = pkj >> 16;
          if (rj != rcur) {            // wave-uniform branch
            if (rcur >= 0) {
              uint p = (uint)fToBf(a0) | ((uint)fToBf(a1) << 16);
              *(uint*)(grow + rcur * 128 + col) = p;
              wmask |= 1u << rcur;
            }
            a0 = 0.f; a1 = 0.f;
            if ((wmask >> rj) & 1) {   // revisit (multi-chunk only; rare)
              uint old = *(const uint*)(grow + rj * 128 + col);
              a0 = bfToF((ushort_t)(old & 0xFFFF));
              a1 = bfToF((ushort_t)(old >> 16));
            }
            rcur = rj;
          }
          a0 += wj * bfToF((ushort_t)(v & 0xFFFF));
          a1 += wj * bfToF((ushort_t)(v >> 16));
          pkj = pkn; v = vn;
        }
      }
      if (rcur >= 0) {
        uint p = (uint)fToBf(a0) | ((uint)fToBf(a1) << 16);
        *(uint*)(grow + rcur * 128 + col) = p;
        wmask |= 1u << rcur;
      }
    }
    #pragma unroll
    for (int r = 0; r < 8; r++)
      if (!((wmask >> r) & 1)) *(uint*)(grow + r * 128 + col) = 0u;
  }
  __syncthreads();

  // ---------------- transform: h = relu(g @ WTcat^T + bias) ----------------
  if (wv < 8) {
    f32x4 acc[2] = {};
    for (int kk = 0; kk < 32; kk++) {
      bf16x8 af = *(const bf16x8*)(WTcat + (size_t)(wv * 16 + l15) * 1024 + kk * 32 + quad * 8);
      bf16x8 b0 = *(const bf16x8*)(gs + (size_t)l15 * 1032 + kk * 32 + quad * 8);
      bf16x8 b1 = *(const bf16x8*)(gs + (size_t)(16 + l15) * 1032 + kk * 32 + quad * 8);
      acc[0] = __builtin_amdgcn_mfma_f32_16x16x32_bf16(af, b0, acc[0], 0, 0, 0);
      acc[1] = __builtin_amdgcn_mfma_f32_16x16x32_bf16(af, b1, acc[1], 0, 0, 0);
    }
    int ch0 = wv * 16 + quad * 4;
    #pragma unroll
    for (int ni = 0; ni < 2; ni++) {
      uint2 p;
      float a0 = fmaxf(acc[ni][0] + bias[ch0], 0.f);
      float a1 = fmaxf(acc[ni][1] + bias[ch0 + 1], 0.f);
      float a2 = fmaxf(acc[ni][2] + bias[ch0 + 2], 0.f);
      float a3 = fmaxf(acc[ni][3] + bias[ch0 + 3], 0.f);
      p.x = (uint)fToBf(a0) | ((uint)fToBf(a1) << 16);
      p.y = (uint)fToBf(a2) | ((uint)fToBf(a3) << 16);
      *(uint2*)(ht + (size_t)(ni * 16 + l15) * 136 + ch0) = p;
    }
  }
  __syncthreads();

  if constexpr (EPI == 1) {
    // store h (coalesced) + next-layer score table
    if (tid < 512) {
      int row = tid >> 4, off = (tid & 15) * 8;
      int t = t0 + row;
      if (t < n)
        *(int4*)(h_out + (size_t)t * 128 + off) = *(const int4*)(ht + (size_t)row * 136 + off);
    }
    if (wv < 2) {
      bf16x8 aq[4];
      #pragma unroll
      for (int kb = 0; kb < 4; kb++)
        aq[kb] = *(const bf16x8*)(wqk2 + (size_t)l15 * 128 + kb * 32 + quad * 8);
      f32x4 a = {};
      #pragma unroll
      for (int kb = 0; kb < 4; kb++) {
        bf16x8 bf = *(const bf16x8*)(ht + (size_t)(wv * 16 + l15) * 136 + kb * 32 + quad * 8);
        a = __builtin_amdgcn_mfma_f32_16x16x32_bf16(aq[kb], bf, a, 0, 0, 0);
      }
      int t = t0 + wv * 16 + l15;
      if (t < n) {
        float4 v = {a[0], a[1], a[2], a[3]};
        *(float4*)(stbl_out + (size_t)t * 16 + quad * 4) = v;
      }
    }
  } else {
    // fused final linear: out = ht @ Wl^T + bl (f32)
    int mi = wv & 7, ni = wv >> 3;
    f32x4 a = {};
    #pragma unroll
    for (int kb = 0; kb < 4; kb++) {
      bf16x8 af = *(const bf16x8*)(wlbf + (size_t)(mi * 16 + l15) * 128 + kb * 32 + quad * 8);
      bf16x8 bf = *(const bf16x8*)(ht + (size_t)(ni * 16 + l15) * 136 + kb * 32 + quad * 8);
      a = __builtin_amdgcn_mfma_f32_16x16x32_bf16(af, bf, a, 0, 0, 0);
    }
    int ch0 = mi * 16 + quad * 4;
    int t = t0 + ni * 16 + l15;
    if (t < n) {
      float4 v = {a[0] + bl[ch0], a[1] + bl[ch0 + 1],
                  a[2] + bl[ch0 + 2], a[3] + bl[ch0 + 3]};
      *(float4*)(out + (size_t)t * 128 + ch0) = v;
    }
  }
}

// ------------------------------- launcher ----------------------------------

extern "C" void kernel_launch(void* const* d_in, const int* in_sizes, int n_in,
                              void* d_out, int out_size, void* d_ws, size_t ws_size,
                              hipStream_t stream) {
  const float* x   = (const float*)d_in[0];
  const int* ei    = (const int*)d_in[1];
  const int* etype = (const int*)d_in[2];
  const float* W1  = (const float*)d_in[4];
  const float* q1  = (const float*)d_in[5];
  const float* k1  = (const float*)d_in[6];
  const float* b1  = (const float*)d_in[7];
  const float* W2  = (const float*)d_in[8];
  const float* q2  = (const float*)d_in[9];
  const float* k2  = (const float*)d_in[10];
  const float* b2  = (const float*)d_in[11];
  const float* Wl  = (const float*)d_in[12];
  const float* bl  = (const float*)d_in[13];
  float* out       = (float*)d_out;

  const int N = in_sizes[0] / 128;   // 50000
  const int E = in_sizes[2];         // 800000

  char* ws = (char*)d_ws;
  size_t off = 0;
  auto alloc = [&](size_t bytes) {
    size_t o = off;
    off = (off + bytes + 255) & ~(size_t)255;
    return o;
  };

  ushort_t* xbf   = (ushort_t*)(ws + alloc((size_t)N * 128 * 2));
  ushort_t* h1    = (ushort_t*)(ws + alloc((size_t)N * 128 * 2));
  ushort_t* WTcat = (ushort_t*)(ws + alloc((size_t)2 * 128 * 1024 * 2));
  ushort_t* wlbf  = (ushort_t*)(ws + alloc(128 * 128 * 2));
  ushort_t* wqk   = (ushort_t*)(ws + alloc(2 * 16 * 128 * 2));
  float* stblA    = (float*)(ws + alloc((size_t)N * 16 * 4));
  float* stblB    = (float*)(ws + alloc((size_t)N * 16 * 4));
  float* wts      = (float*)(ws + alloc((size_t)E * 4));
  int* sorted2    = (int*)(ws + alloc((size_t)E * 4));
  int* deg        = (int*)(ws + alloc((size_t)N * 4));
  int* cursor     = (int*)(ws + alloc((size_t)N * 4));
  int* incl       = (int*)(ws + alloc((size_t)N * 4));
  int* rowptr     = (int*)(ws + alloc((size_t)(N + 1) * 4));
  int* bsum       = (int*)(ws + alloc(256 * 4));
  int* sorted     = (int*)(ws + alloc((size_t)E * 4));
  (void)ws_size; (void)n_in; (void)out_size;

  const int* srcp = ei;
  const int* tgtp = ei + E;

  int gE = (E + 255) / 256;
  int gN = (N + 255) / 256;
  int gS = (N + 127) / 128;     // k_stbl
  int gW = (N + 3) / 4;         // k_weights: 12500
  int gF = (N + 31) / 32;       // k_layer: 1563

  // CSR build (once; same graph both layers)
  hipMemsetAsync(deg, 0, (size_t)N * 4, stream);
  hipMemsetAsync(cursor, 0, (size_t)N * 4, stream);
  k_count<<<gE, 256, 0, stream>>>(tgtp, deg, E);
  k_scanA<<<gN, 256, 0, stream>>>(deg, incl, bsum, N);
  k_scanB<<<1, 256, 0, stream>>>(bsum, gN);
  k_scanC<<<gN, 256, 0, stream>>>(deg, incl, bsum, rowptr, N, E);
  k_scatter<<<gE, 256, 0, stream>>>(srcp, tgtp, etype, rowptr, cursor, sorted, E);

  // conversions + weight prep
  k_cvt<<<(N * 128 / 4 + 255) / 256, 256, 0, stream>>>(x, xbf, N * 128 / 4);
  k_cvt<<<(128 * 128 / 4 + 255) / 256, 256, 0, stream>>>(Wl, wlbf, 128 * 128 / 4);
  k_wT<<<2048, 128, 0, stream>>>(W1, W2, WTcat);
  k_wqwk<<<16, 256, 0, stream>>>(W1, q1, k1, W2, q2, k2, wqk);

  // layer-1 score table
  k_stbl<<<gS, 256, 0, stream>>>(xbf, wqk, stblA, N);

  // layer 1
  k_weights<<<gW, 256, 0, stream>>>(stblA, rowptr, sorted, sorted2, wts, N);
  k_layer<1><<<gF, 1024, 0, stream>>>(xbf, rowptr, sorted2, wts, WTcat, b1,
                                      wqk + 2048, stblB, h1,
                                      nullptr, nullptr, nullptr, N);
  // layer 2 (+ fused final linear)
  k_weights<<<gW, 256, 0, stream>>>(stblB, rowptr, sorted, sorted2, wts, N);
  k_layer<2><<<gF, 1024, 0, stream>>>(h1, rowptr, sorted2, wts,
                                      WTcat + (size_t)128 * 1024, b2,
                                      nullptr, nullptr, nullptr,
                                      wlbf, bl, out, N);
}